// Round 1
// baseline (267.986 us; speedup 1.0000x reference)
//
#include <hip/hip_runtime.h>
#include <math.h>

// SoftPeakAwareLoss on MI355X.
// One thread per (batch, day): loads 24 fp32 yp/yt/dm as 6x float4 each,
// computes all four loss components in registers, block-reduces to a float4
// partial per block (d_ws), then a single-block finalize kernel combines.

#define HOURS_ 24
#define WIN_ 2
#define NEGV (-1e9f)

__global__ __launch_bounds__(256) void splloss_days(
    const float* __restrict__ ypred,
    const float* __restrict__ ytrue,
    const float* __restrict__ isday,
    float4* __restrict__ partials,
    int n_days)
{
    int g = blockIdx.x * 256 + threadIdx.x;
    float o = 0.f, mg = 0.f, tl = 0.f, sh = 0.f;

    if (g < n_days) {
        float a[HOURS_];  // pred
        float b[HOURS_];  // true
        unsigned dmask = 0u;
        const float4* p4 = reinterpret_cast<const float4*>(ypred + (size_t)g * HOURS_);
        const float4* t4 = reinterpret_cast<const float4*>(ytrue + (size_t)g * HOURS_);
        const float4* d4 = reinterpret_cast<const float4*>(isday + (size_t)g * HOURS_);
        #pragma unroll
        for (int k = 0; k < 6; ++k) {
            float4 vp = p4[k];
            float4 vt = t4[k];
            float4 vd = d4[k];
            a[4*k+0] = vp.x; a[4*k+1] = vp.y; a[4*k+2] = vp.z; a[4*k+3] = vp.w;
            b[4*k+0] = vt.x; b[4*k+1] = vt.y; b[4*k+2] = vt.z; b[4*k+3] = vt.w;
            dmask |= (vd.x > 0.5f ? 1u : 0u) << (4*k+0);
            dmask |= (vd.y > 0.5f ? 1u : 0u) << (4*k+1);
            dmask |= (vd.z > 0.5f ? 1u : 0u) << (4*k+2);
            dmask |= (vd.w > 0.5f ? 1u : 0u) << (4*k+3);
        }

        // ---- L_overall partial: sum of squared diffs over this day's 24 hours
        #pragma unroll
        for (int h = 0; h < HOURS_; ++h) { float d = a[h] - b[h]; o += d * d; }

        // ---- masked maxima; first-occurrence argmax on masked true
        float mt = -INFINITY, mp = -INFINITY;
        int peak = 0;
        #pragma unroll
        for (int h = 0; h < HOURS_; ++h) {
            bool day = (dmask >> h) & 1u;
            float bm = day ? b[h] : NEGV;
            float am = day ? a[h] : NEGV;
            if (bm > mt) { mt = bm; peak = h; }   // strict > keeps first occurrence
            mp = fmaxf(mp, am);
        }

        // ---- soft peaks (softmax with TEMP=0.1 -> scale 10)
        float set = 0.f, syt = 0.f, sht = 0.f;
        float sep = 0.f, syp = 0.f, shp = 0.f;
        #pragma unroll
        for (int h = 0; h < HOURS_; ++h) {
            bool day = (dmask >> h) & 1u;
            float bm = day ? b[h] : NEGV;
            float am = day ? a[h] : NEGV;
            float et = __expf((bm - mt) * 10.f);   // night lanes -> exp(-1e10) = 0
            float ep = __expf((am - mp) * 10.f);
            set += et; syt += et * b[h]; sht += et * (float)h;
            sep += ep; syp += ep * a[h]; shp += ep * (float)h;
        }
        float tv = syt / set, tt = sht / set;
        float pv = syp / sep, pt = shp / sep;
        mg = (pv - tv) * (pv - tv);
        tl = (pt - tt) * (pt - tt);

        // ---- shape loss: +-WIN window around hard argmax of masked true.
        // Runtime index -> cndmask select chain (keeps a[],b[] in registers).
        float tw[5], pw[5];
        bool  val[5];
        float tmax = -INFINITY, pmax = -INFINITY, cnt = 0.f;
        #pragma unroll
        for (int j = 0; j < 5; ++j) {
            int idx = peak + j - WIN_;
            bool v = (idx >= 0) && (idx < HOURS_);
            int ic = idx < 0 ? 0 : (idx > HOURS_ - 1 ? HOURS_ - 1 : idx);
            float tg = b[0], pg = a[0];
            #pragma unroll
            for (int h = 1; h < HOURS_; ++h) {
                bool e = (ic == h);
                tg = e ? b[h] : tg;
                pg = e ? a[h] : pg;
            }
            tw[j] = tg; pw[j] = pg; val[j] = v;
            if (v) { tmax = fmaxf(tmax, tg); pmax = fmaxf(pmax, pg); cnt += 1.f; }
        }
        float rt = 1.f / (tmax + 1e-6f);
        float rp = 1.f / (pmax + 1e-6f);
        float ss = 0.f;
        #pragma unroll
        for (int j = 0; j < 5; ++j) {
            float tn = tw[j] * rt, pn = pw[j] * rp;
            float d = pn - tn;
            ss += val[j] ? d * d : 0.f;
        }
        sh = ss / cnt;
    }

    // ---- block reduction: wave shuffle then LDS across the 4 waves
    #pragma unroll
    for (int off = 32; off > 0; off >>= 1) {
        o  += __shfl_down(o,  off);
        mg += __shfl_down(mg, off);
        tl += __shfl_down(tl, off);
        sh += __shfl_down(sh, off);
    }
    __shared__ float4 red[4];
    int wid = threadIdx.x >> 6;
    if ((threadIdx.x & 63) == 0) red[wid] = make_float4(o, mg, tl, sh);
    __syncthreads();
    if (threadIdx.x == 0) {
        float4 r0 = red[0], r1 = red[1], r2 = red[2], r3 = red[3];
        partials[blockIdx.x] = make_float4(r0.x + r1.x + r2.x + r3.x,
                                           r0.y + r1.y + r2.y + r3.y,
                                           r0.z + r1.z + r2.z + r3.z,
                                           r0.w + r1.w + r2.w + r3.w);
    }
}

__global__ __launch_bounds__(256) void splloss_final(
    const float4* __restrict__ partials, int nb, float* __restrict__ out,
    double inv_bs, double inv_bd, double inv_shape)
{
    double o = 0.0, m = 0.0, t = 0.0, s = 0.0;
    for (int i = threadIdx.x; i < nb; i += 256) {
        float4 p = partials[i];
        o += (double)p.x; m += (double)p.y; t += (double)p.z; s += (double)p.w;
    }
    #pragma unroll
    for (int off = 32; off > 0; off >>= 1) {
        o += __shfl_down(o, off);
        m += __shfl_down(m, off);
        t += __shfl_down(t, off);
        s += __shfl_down(s, off);
    }
    __shared__ double red[4][4];
    int wid = threadIdx.x >> 6;
    if ((threadIdx.x & 63) == 0) { red[wid][0] = o; red[wid][1] = m; red[wid][2] = t; red[wid][3] = s; }
    __syncthreads();
    if (threadIdx.x == 0) {
        double ot = red[0][0] + red[1][0] + red[2][0] + red[3][0];
        double mt = red[0][1] + red[1][1] + red[2][1] + red[3][1];
        double tt = red[0][2] + red[1][2] + red[2][2] + red[3][2];
        double st = red[0][3] + red[1][3] + red[2][3] + red[3][3];
        // ALPHA=1, BETA=2, GAMMA=1, DELTA=0.5
        double total = 1.0 * (ot * inv_bs)
                     + 2.0 * (mt * inv_bd)
                     + 1.0 * (tt * inv_bd)
                     + 0.5 * (st * inv_shape);
        out[0] = (float)total;
    }
}

extern "C" void kernel_launch(void* const* d_in, const int* in_sizes, int n_in,
                              void* d_out, int out_size, void* d_ws, size_t ws_size,
                              hipStream_t stream) {
    const float* yp = (const float*)d_in[0];
    const float* yt = (const float*)d_in[1];
    const float* dm = (const float*)d_in[2];
    float* out = (float*)d_out;

    int n = in_sizes[0];              // B*S; S=1440 divisible by 24, so days tile exactly
    int n_days = n / HOURS_;          // B*D
    int nb = (n_days + 255) / 256;

    float4* partials = (float4*)d_ws; // nb * 16 bytes

    splloss_days<<<nb, 256, 0, stream>>>(yp, yt, dm, partials, n_days);

    double inv_bs    = 1.0 / (double)n;
    double inv_bd    = 1.0 / (double)n_days;
    double inv_shape = 1.0 / ((double)n_days + 1e-6);
    splloss_final<<<1, 256, 0, stream>>>(partials, nb, out, inv_bs, inv_bd, inv_shape);
}